// Round 3
// baseline (151.589 us; speedup 1.0000x reference)
//
#include <hip/hip_runtime.h>

// Problem constants (B, L, NSESS, S, H) = (16, 512, 4, 512, 512)
constexpr int B     = 16;
constexpr int L     = 512;
constexpr int NSESS = 4;
constexpr int S     = 512;
constexpr int H     = 512;
constexpr int HV    = H / 4;   // 128 float4 per row

// Clang-native vector type (HIP's float4 is a struct; the nontemporal
// builtins require a real vector type). Lowers to dwordx4 loads/stores.
typedef float vf4 __attribute__((ext_vector_type(4)));

// One block per (b, l). 128 threads: lane j handles float4 column j of all
// 5 gathered rows. Rows are 2 KB contiguous -> fully coalesced loads/stores.
//
// R3 (= R2 intent, compile-fixed):
//  - nontemporal stores: the 84 MB output stream bypasses cache residency,
//    keeping the 67 MB session_repre gather working set hot in L2/L3.
//  - XCD swizzle: blockIdx round-robins across 8 XCDs; remap so each XCD
//    gets a contiguous 1024-bl range (2 batches, 8.4 MB) for L2 locality.
__global__ __launch_bounds__(128)
void state_matrix_encoder_kernel(const float* __restrict__ sess_repre,
                                 const int*   __restrict__ stm,
                                 float*       __restrict__ out)
{
    const int raw = blockIdx.x;                     // 0 .. 8191
    const int bl  = ((raw & 7) << 10) | (raw >> 3); // XCD-contiguous remap
    const int b   = bl >> 9;                        // bl / L   (L = 512)
    const int j   = threadIdx.x;                    // float4 column, 0..127

    // 5 indices for this (b, l); wave-uniform (scalar-broadcast loads)
    const int* stm_bl = stm + bl * 5;
    const int p0 = stm_bl[0] - 1;     // session 3
    const int p1 = stm_bl[1] - 1;     // session 0
    const int p2 = stm_bl[2] - 1;     // session 1
    const int p3 = stm_bl[3] - 1;     // session 2
    const int p4 = stm_bl[4] - 1;     // session 3

    const vf4* base = (const vf4*)sess_repre
                    + (size_t)b * (size_t)(NSESS * S * HV);

    const vf4 v0 = base[(size_t)(3 * S + p0) * HV + j];
    const vf4 v1 = base[(size_t)(0 * S + p1) * HV + j];
    const vf4 v2 = base[(size_t)(1 * S + p2) * HV + j];
    const vf4 v3 = base[(size_t)(2 * S + p3) * HV + j];
    const vf4 v4 = base[(size_t)(3 * S + p4) * HV + j];

    const vf4 m = (v0 + v1 + v2 + v3) * 0.25f;

    vf4* o = (vf4*)out + (size_t)bl * (size_t)(5 * HV) + j;
    __builtin_nontemporal_store(m,  &o[0 * HV]);
    __builtin_nontemporal_store(v1, &o[1 * HV]);
    __builtin_nontemporal_store(v2, &o[2 * HV]);
    __builtin_nontemporal_store(v3, &o[3 * HV]);
    __builtin_nontemporal_store(v4, &o[4 * HV]);
}

extern "C" void kernel_launch(void* const* d_in, const int* in_sizes, int n_in,
                              void* d_out, int out_size, void* d_ws, size_t ws_size,
                              hipStream_t stream)
{
    // Input order (setup_inputs dict order):
    //   0: utterance_repre    (B, L, H)        float32  -- unused
    //   1: conversation_repre (B, H)           float32  -- unused
    //   2: session_repre      (B, NSESS, S, H) float32
    //   3: state_transition_matrix (B, L, 5)   int (harness stages ints as int32)
    //   4: max_conversation_length scalar      int      -- == L, unused
    const float* sess_repre = (const float*)d_in[2];
    const int*   stm        = (const int*)d_in[3];
    float*       out        = (float*)d_out;

    dim3 grid(B * L);   // 8192 blocks
    dim3 block(HV);     // 128 threads
    state_matrix_encoder_kernel<<<grid, block, 0, stream>>>(sess_repre, stm, out);
}

// Round 4
// 146.894 us; speedup vs baseline: 1.0320x; 1.0320x over previous
//
#include <hip/hip_runtime.h>

// Problem constants (B, L, NSESS, S, H) = (16, 512, 4, 512, 512)
constexpr int B     = 16;
constexpr int L     = 512;
constexpr int NSESS = 4;
constexpr int S     = 512;
constexpr int H     = 512;
constexpr int HV    = H / 4;   // 128 float4 per row

// Clang-native vector type -> guaranteed global_load/store_dwordx4.
typedef float vf4 __attribute__((ext_vector_type(4)));

// One block per (b, l). 128 threads: lane j handles float4 column j of all
// 5 gathered rows. Rows are 2 KB contiguous -> fully coalesced 1 KB/wave
// transactions for both loads and stores.
//
// R4 = revert to R1 config (empirically best: 145.8 µs vs 151.6 with
// nt-stores+swizzle). Plain cached stores; natural block order. Measured:
// nt stores / XCD swizzle were neutral-to-negative — session_repre (67 MB)
// is L3-resident (die-level cache), so per-XCD locality games don't pay.
__global__ __launch_bounds__(128)
void state_matrix_encoder_kernel(const float* __restrict__ sess_repre,
                                 const int*   __restrict__ stm,
                                 float*       __restrict__ out)
{
    const int bl = blockIdx.x;        // 0 .. B*L-1
    const int b  = bl >> 9;           // bl / L   (L = 512)
    const int j  = threadIdx.x;       // float4 column, 0..127

    // 5 indices for this (b, l); wave-uniform (scalar-broadcast loads)
    const int* stm_bl = stm + bl * 5;
    const int p0 = stm_bl[0] - 1;     // session 3
    const int p1 = stm_bl[1] - 1;     // session 0
    const int p2 = stm_bl[2] - 1;     // session 1
    const int p3 = stm_bl[3] - 1;     // session 2
    const int p4 = stm_bl[4] - 1;     // session 3

    const vf4* base = (const vf4*)sess_repre
                    + (size_t)b * (size_t)(NSESS * S * HV);

    const vf4 v0 = base[(size_t)(3 * S + p0) * HV + j];
    const vf4 v1 = base[(size_t)(0 * S + p1) * HV + j];
    const vf4 v2 = base[(size_t)(1 * S + p2) * HV + j];
    const vf4 v3 = base[(size_t)(2 * S + p3) * HV + j];
    const vf4 v4 = base[(size_t)(3 * S + p4) * HV + j];

    const vf4 m = (v0 + v1 + v2 + v3) * 0.25f;

    vf4* o = (vf4*)out + (size_t)bl * (size_t)(5 * HV) + j;
    o[0 * HV] = m;
    o[1 * HV] = v1;
    o[2 * HV] = v2;
    o[3 * HV] = v3;
    o[4 * HV] = v4;
}

extern "C" void kernel_launch(void* const* d_in, const int* in_sizes, int n_in,
                              void* d_out, int out_size, void* d_ws, size_t ws_size,
                              hipStream_t stream)
{
    // Input order (setup_inputs dict order):
    //   0: utterance_repre    (B, L, H)        float32  -- unused
    //   1: conversation_repre (B, H)           float32  -- unused
    //   2: session_repre      (B, NSESS, S, H) float32
    //   3: state_transition_matrix (B, L, 5)   int (harness stages ints as int32)
    //   4: max_conversation_length scalar      int      -- == L, unused
    const float* sess_repre = (const float*)d_in[2];
    const int*   stm        = (const int*)d_in[3];
    float*       out        = (float*)d_out;

    dim3 grid(B * L);   // 8192 blocks
    dim3 block(HV);     // 128 threads
    state_matrix_encoder_kernel<<<grid, block, 0, stream>>>(sess_repre, stm, out);
}